// Round 1
// baseline (5482.118 us; speedup 1.0000x reference)
//
#include <hip/hip_runtime.h>
#include <math.h>

#define N 8192
#define C 128
#define NC 256
#define KNN 5

#define TI 32
#define TJ 64
#define TC 32

static __device__ __forceinline__ unsigned rotl32(unsigned x, unsigned r) {
    return (x << r) | (x >> (32u - r));
}

// ---------------------------------------------------------------------------
// init: zero the global d2max accumulator
// ---------------------------------------------------------------------------
__global__ void init_kernel(unsigned long long* d2max) {
    *d2max = 0ull;
}

// ---------------------------------------------------------------------------
// sq[i] = sum_c (double)x[i][c]^2   (one wave per row)
// ---------------------------------------------------------------------------
__global__ void sq_kernel(const float* __restrict__ X, double* __restrict__ sq) {
    int wave = (blockIdx.x * blockDim.x + threadIdx.x) >> 6;
    int lane = threadIdx.x & 63;
    if (wave >= N) return;
    double v0 = (double)X[wave * C + lane];
    double v1 = (double)X[wave * C + 64 + lane];
    double s = v0 * v0 + v1 * v1;
    #pragma unroll
    for (int off = 32; off > 0; off >>= 1) s += __shfl_down(s, off, 64);
    if (lane == 0) sq[wave] = s;
}

// ---------------------------------------------------------------------------
// JAX threefry2x32 replication: jax.random.uniform(jax.random.key(1), (1,8192))
// key = (0,1); counts = iota(8192) split into halves (j, j+4096).
// ---------------------------------------------------------------------------
__global__ void noise_kernel(float* __restrict__ noise) {
    int j = blockIdx.x * blockDim.x + threadIdx.x;
    if (j >= N / 2) return;
    const unsigned ks0 = 0u, ks1 = 1u;
    const unsigned ks2 = 0x1BD11BDAu ^ ks0 ^ ks1;
    unsigned x0 = (unsigned)j + ks0;
    unsigned x1 = (unsigned)(j + N / 2) + ks1;
    const unsigned rotA[4] = {13u, 15u, 26u, 6u};
    const unsigned rotB[4] = {17u, 29u, 16u, 24u};
    #pragma unroll
    for (int r = 0; r < 4; r++) { x0 += x1; x1 = rotl32(x1, rotA[r]); x1 ^= x0; }
    x0 += ks1; x1 += ks2 + 1u;
    #pragma unroll
    for (int r = 0; r < 4; r++) { x0 += x1; x1 = rotl32(x1, rotB[r]); x1 ^= x0; }
    x0 += ks2; x1 += ks0 + 2u;
    #pragma unroll
    for (int r = 0; r < 4; r++) { x0 += x1; x1 = rotl32(x1, rotA[r]); x1 ^= x0; }
    x0 += ks0; x1 += ks1 + 3u;
    #pragma unroll
    for (int r = 0; r < 4; r++) { x0 += x1; x1 = rotl32(x1, rotB[r]); x1 ^= x0; }
    x0 += ks1; x1 += ks2 + 4u;
    #pragma unroll
    for (int r = 0; r < 4; r++) { x0 += x1; x1 = rotl32(x1, rotA[r]); x1 ^= x0; }
    x0 += ks2; x1 += ks0 + 5u;
    unsigned b0 = (x0 >> 9) | 0x3f800000u;
    unsigned b1 = (x1 >> 9) | 0x3f800000u;
    noise[j]         = __uint_as_float(b0) - 1.0f;
    noise[j + N / 2] = __uint_as_float(b1) - 1.0f;
}

// ---------------------------------------------------------------------------
// Pass A: per-row 5 smallest raw d2 (monotone proxy for dist) -> density,
// plus global max d2 (for dist_max).
// d2[i][j] = sq[i] + sq[j] - 2*dot(x_i, x_j), all fp64.
// ---------------------------------------------------------------------------
__launch_bounds__(256)
__global__ void density_kernel(const float* __restrict__ X,
                               const double* __restrict__ sq,
                               const float* __restrict__ noise,
                               double* __restrict__ density,
                               unsigned long long* __restrict__ d2max_p)
{
    __shared__ double As[TC][TI + 1];
    __shared__ double Bs[TC][TJ + 1];
    __shared__ double Ts[TI][TJ + 1];

    const int t  = threadIdx.x;
    const int tx = t & 15;    // j-group of 4
    const int ty = t >> 4;    // i-group of 2
    const int i0 = blockIdx.x * TI;

    double t5[KNN];
    #pragma unroll
    for (int k = 0; k < KNN; k++) t5[k] = 1e300;
    double rowmax = 0.0;

    double sqa0 = sq[i0 + 2 * ty];
    double sqa1 = sq[i0 + 2 * ty + 1];

    for (int j0 = 0; j0 < N; j0 += TJ) {
        double acc[2][4];
        #pragma unroll
        for (int r = 0; r < 2; r++)
            #pragma unroll
            for (int s = 0; s < 4; s++) acc[r][s] = 0.0;

        for (int c0 = 0; c0 < C; c0 += TC) {
            __syncthreads();
            #pragma unroll
            for (int k = 0; k < 4; k++) {
                int flat = t + 256 * k;            // 0..1023 = 32 rows x 32 c
                int r = flat >> 5, c = flat & 31;
                As[c][r] = (double)X[(i0 + r) * C + c0 + c];
            }
            #pragma unroll
            for (int k = 0; k < 8; k++) {
                int flat = t + 256 * k;            // 0..2047 = 64 rows x 32 c
                int r = flat >> 5, c = flat & 31;
                Bs[c][r] = (double)X[(j0 + r) * C + c0 + c];
            }
            __syncthreads();
            #pragma unroll
            for (int c = 0; c < TC; c++) {
                double a0 = As[c][2 * ty], a1 = As[c][2 * ty + 1];
                double b0 = Bs[c][4 * tx], b1 = Bs[c][4 * tx + 1];
                double b2 = Bs[c][4 * tx + 2], b3 = Bs[c][4 * tx + 3];
                acc[0][0] += a0 * b0; acc[0][1] += a0 * b1;
                acc[0][2] += a0 * b2; acc[0][3] += a0 * b3;
                acc[1][0] += a1 * b0; acc[1][1] += a1 * b1;
                acc[1][2] += a1 * b2; acc[1][3] += a1 * b3;
            }
        }
        __syncthreads();
        #pragma unroll
        for (int s = 0; s < 4; s++) {
            int lj = 4 * tx + s;
            double sqb = sq[j0 + lj];
            Ts[2 * ty][lj]     = sqa0 + sqb - 2.0 * acc[0][s];
            Ts[2 * ty + 1][lj] = sqa1 + sqb - 2.0 * acc[1][s];
        }
        __syncthreads();
        if (t < TI) {
            for (int jj = 0; jj < TJ; jj++) {
                double v = Ts[t][jj];
                rowmax = fmax(rowmax, v);
                if (v < t5[0]) {   // t5[0] holds current max of the 5
                    t5[0] = v;
                    #pragma unroll
                    for (int k = 1; k < KNN; k++)
                        if (t5[k] > t5[0]) { double tmp = t5[0]; t5[0] = t5[k]; t5[k] = tmp; }
                }
            }
        }
    }

    if (t < TI) {
        // sort ascending to mimic reference's summation order of sorted top-k
        for (int a = 1; a < KNN; a++) {
            double key = t5[a]; int b = a - 1;
            while (b >= 0 && t5[b] > key) { t5[b + 1] = t5[b]; b--; }
            t5[b + 1] = key;
        }
        double s2 = 0.0;
        #pragma unroll
        for (int k = 0; k < KNN; k++) {
            double z = t5[k] > 0.0 ? t5[k] : 0.0;
            double d = sqrt(z) / 11.313708498984761;   // dist as in reference
            s2 += d * d;                                // (neg_k)^2
        }
        double m = s2 / 5.0;
        double dens = exp(-m) + (double)(noise[i0 + t] * 1e-6f);
        density[i0 + t] = dens;
        rowmax = fmax(rowmax, 0.0);   // keep sign bit clear for uint ordering
        atomicMax(d2max_p, (unsigned long long)__double_as_longlong(rowmax));
    }
}

// ---------------------------------------------------------------------------
// Pass B: dist_parent[i] = min over {j : density[j] > density[i]} of dist,
// else dist_max; score[i] = dist_parent[i] * density[i].
// ---------------------------------------------------------------------------
__launch_bounds__(256)
__global__ void parent_kernel(const float* __restrict__ X,
                              const double* __restrict__ sq,
                              const double* __restrict__ density,
                              const unsigned long long* __restrict__ d2max_p,
                              double* __restrict__ score)
{
    __shared__ double As[TC][TI + 1];
    __shared__ double Bs[TC][TJ + 1];
    __shared__ double Ts[TI][TJ + 1];
    __shared__ double Ds[TJ];

    const int t  = threadIdx.x;
    const int tx = t & 15;
    const int ty = t >> 4;
    const int i0 = blockIdx.x * TI;

    double di = (t < TI) ? density[i0 + t] : 0.0;
    double dmin = 1e300;

    double sqa0 = sq[i0 + 2 * ty];
    double sqa1 = sq[i0 + 2 * ty + 1];

    for (int j0 = 0; j0 < N; j0 += TJ) {
        double acc[2][4];
        #pragma unroll
        for (int r = 0; r < 2; r++)
            #pragma unroll
            for (int s = 0; s < 4; s++) acc[r][s] = 0.0;

        for (int c0 = 0; c0 < C; c0 += TC) {
            __syncthreads();
            if (c0 == 0 && t < TJ) Ds[t] = density[j0 + t];
            #pragma unroll
            for (int k = 0; k < 4; k++) {
                int flat = t + 256 * k;
                int r = flat >> 5, c = flat & 31;
                As[c][r] = (double)X[(i0 + r) * C + c0 + c];
            }
            #pragma unroll
            for (int k = 0; k < 8; k++) {
                int flat = t + 256 * k;
                int r = flat >> 5, c = flat & 31;
                Bs[c][r] = (double)X[(j0 + r) * C + c0 + c];
            }
            __syncthreads();
            #pragma unroll
            for (int c = 0; c < TC; c++) {
                double a0 = As[c][2 * ty], a1 = As[c][2 * ty + 1];
                double b0 = Bs[c][4 * tx], b1 = Bs[c][4 * tx + 1];
                double b2 = Bs[c][4 * tx + 2], b3 = Bs[c][4 * tx + 3];
                acc[0][0] += a0 * b0; acc[0][1] += a0 * b1;
                acc[0][2] += a0 * b2; acc[0][3] += a0 * b3;
                acc[1][0] += a1 * b0; acc[1][1] += a1 * b1;
                acc[1][2] += a1 * b2; acc[1][3] += a1 * b3;
            }
        }
        __syncthreads();
        #pragma unroll
        for (int s = 0; s < 4; s++) {
            int lj = 4 * tx + s;
            double sqb = sq[j0 + lj];
            Ts[2 * ty][lj]     = sqa0 + sqb - 2.0 * acc[0][s];
            Ts[2 * ty + 1][lj] = sqa1 + sqb - 2.0 * acc[1][s];
        }
        __syncthreads();
        if (t < TI) {
            for (int jj = 0; jj < TJ; jj++) {
                double v = Ts[t][jj];
                if (Ds[jj] > di) dmin = fmin(dmin, v);
            }
        }
    }

    if (t < TI) {
        double d2m = __longlong_as_double((long long)(*d2max_p));
        double distmax = sqrt(fmax(d2m, 0.0)) / 11.313708498984761;
        double dp;
        if (dmin > 9.9e299) {
            dp = distmax;   // no higher-density point (global density max)
        } else {
            dp = sqrt(fmax(dmin, 0.0)) / 11.313708498984761;
        }
        score[i0 + t] = dp * di;
    }
}

// ---------------------------------------------------------------------------
// Stable descending rank (matches lax.top_k tie semantics); out[rank] = i.
// ---------------------------------------------------------------------------
__launch_bounds__(256)
__global__ void rank_kernel(const double* __restrict__ score, int* __restrict__ out)
{
    __shared__ double Ss[N];
    #pragma unroll
    for (int k = 0; k < N / 256; k++) {
        int idx = threadIdx.x + 256 * k;
        Ss[idx] = score[idx];
    }
    __syncthreads();
    int i = blockIdx.x * 256 + threadIdx.x;
    double si = Ss[i];
    int rank = 0;
    for (int j = 0; j < N; j++) {
        double sj = Ss[j];
        rank += (sj > si) || (sj == si && j < i);
    }
    if (rank < NC) out[rank] = i;
}

// ---------------------------------------------------------------------------
extern "C" void kernel_launch(void* const* d_in, const int* in_sizes, int n_in,
                              void* d_out, int out_size, void* d_ws, size_t ws_size,
                              hipStream_t stream) {
    const float* X = (const float*)d_in[0];
    int* out = (int*)d_out;

    double* ws      = (double*)d_ws;
    double* sq      = ws;                 // 8192 doubles
    double* density = ws + 8192;          // 8192 doubles
    double* score   = ws + 16384;         // 8192 doubles
    unsigned long long* d2max = (unsigned long long*)(ws + 24576);
    float* noise    = (float*)(ws + 24577);  // 8192 floats

    init_kernel<<<1, 1, 0, stream>>>(d2max);
    sq_kernel<<<N / 4, 256, 0, stream>>>(X, sq);
    noise_kernel<<<(N / 2) / 256, 256, 0, stream>>>(noise);
    density_kernel<<<N / TI, 256, 0, stream>>>(X, sq, noise, density, d2max);
    parent_kernel<<<N / TI, 256, 0, stream>>>(X, sq, density, d2max, score);
    rank_kernel<<<N / 256, 256, 0, stream>>>(score, out);
}

// Round 2
// 1383.595 us; speedup vs baseline: 3.9622x; 3.9622x over previous
//
#include <hip/hip_runtime.h>
#include <math.h>

#define N 8192
#define C 128
#define NC 256
#define KNN 5

#define TI 64
#define TJ 64
#define JSPLIT 8
#define JTILES ((N / JSPLIT) / TJ)   // 16
#define LDSROW 68                    // floats per LDS row: 16B-aligned, conflict-light
#define INV_SQRT_C 11.313708498984761

static __device__ __forceinline__ unsigned rotl32(unsigned x, unsigned r) {
    return (x << r) | (x >> (32u - r));
}

// ---------------------------------------------------------------------------
__global__ void init_kernel(unsigned long long* d2max) { *d2max = 0ull; }

// ---------------------------------------------------------------------------
// sq[i] = sum_c (double)x[i][c]^2   (one wave per row)  -- identical to R1
// ---------------------------------------------------------------------------
__global__ void sq_kernel(const float* __restrict__ X, double* __restrict__ sq) {
    int wave = (blockIdx.x * blockDim.x + threadIdx.x) >> 6;
    int lane = threadIdx.x & 63;
    if (wave >= N) return;
    double v0 = (double)X[wave * C + lane];
    double v1 = (double)X[wave * C + 64 + lane];
    double s = v0 * v0 + v1 * v1;
    #pragma unroll
    for (int off = 32; off > 0; off >>= 1) s += __shfl_down(s, off, 64);
    if (lane == 0) sq[wave] = s;
}

// ---------------------------------------------------------------------------
// JAX threefry2x32: uniform(key(1), (1,8192))  -- identical to R1
// ---------------------------------------------------------------------------
__global__ void noise_kernel(float* __restrict__ noise) {
    int j = blockIdx.x * blockDim.x + threadIdx.x;
    if (j >= N / 2) return;
    const unsigned ks0 = 0u, ks1 = 1u;
    const unsigned ks2 = 0x1BD11BDAu ^ ks0 ^ ks1;
    unsigned x0 = (unsigned)j + ks0;
    unsigned x1 = (unsigned)(j + N / 2) + ks1;
    const unsigned rotA[4] = {13u, 15u, 26u, 6u};
    const unsigned rotB[4] = {17u, 29u, 16u, 24u};
    #pragma unroll
    for (int r = 0; r < 4; r++) { x0 += x1; x1 = rotl32(x1, rotA[r]); x1 ^= x0; }
    x0 += ks1; x1 += ks2 + 1u;
    #pragma unroll
    for (int r = 0; r < 4; r++) { x0 += x1; x1 = rotl32(x1, rotB[r]); x1 ^= x0; }
    x0 += ks2; x1 += ks0 + 2u;
    #pragma unroll
    for (int r = 0; r < 4; r++) { x0 += x1; x1 = rotl32(x1, rotA[r]); x1 ^= x0; }
    x0 += ks0; x1 += ks1 + 3u;
    #pragma unroll
    for (int r = 0; r < 4; r++) { x0 += x1; x1 = rotl32(x1, rotB[r]); x1 ^= x0; }
    x0 += ks1; x1 += ks2 + 4u;
    #pragma unroll
    for (int r = 0; r < 4; r++) { x0 += x1; x1 = rotl32(x1, rotA[r]); x1 ^= x0; }
    x0 += ks2; x1 += ks0 + 5u;
    unsigned b0 = (x0 >> 9) | 0x3f800000u;
    unsigned b1 = (x1 >> 9) | 0x3f800000u;
    noise[j]         = __uint_as_float(b0) - 1.0f;
    noise[j + N / 2] = __uint_as_float(b1) - 1.0f;
}

// ---------------------------------------------------------------------------
// Pass A (partial): per block = (i-tile of 64) x (j-slice of 1024).
// Each thread owns 4 rows x 4 cols; maintains per-row top-5 smallest d2 and
// running max d2 entirely in registers. Block merge -> partial top5 + atomicMax.
// ---------------------------------------------------------------------------
__launch_bounds__(256, 2)
__global__ void density_partial_kernel(const float* __restrict__ X,
                                       const double* __restrict__ sq,
                                       double* __restrict__ top5part,  // [JSPLIT][N][5]
                                       unsigned long long* __restrict__ d2max_p)
{
    __shared__ __align__(16) float S[2 * C * LDSROW];  // As | Bs, c-major [c][i]
    __shared__ double Sqj[TJ];
    __shared__ double wmax[4];
    float* As = S;
    float* Bs = S + C * LDSROW;

    const int t  = threadIdx.x;
    const int tx = t & 15;     // j group (4 cols)
    const int ty = t >> 4;     // i group (4 rows)
    const int i0 = (blockIdx.x & 127) * TI;
    const int js = blockIdx.x >> 7;
    const int jbase = js * (N / JSPLIT);

    const float4* X4 = (const float4*)X;

    // stage A tile (once): global float4 coalesced -> transposed LDS [c][i]
    #pragma unroll
    for (int q = 0; q < 8; q++) {
        int flat = t + 256 * q;
        int row = flat >> 5, c4 = flat & 31;
        float4 v = X4[(size_t)(i0 + row) * 32 + c4];
        float* dst = &As[(4 * c4) * LDSROW + row];
        dst[0 * LDSROW] = v.x; dst[1 * LDSROW] = v.y;
        dst[2 * LDSROW] = v.z; dst[3 * LDSROW] = v.w;
    }

    double sqa[4];
    #pragma unroll
    for (int r = 0; r < 4; r++) sqa[r] = sq[i0 + 4 * ty + r];

    double t5[4][KNN];
    #pragma unroll
    for (int r = 0; r < 4; r++)
        #pragma unroll
        for (int k = 0; k < KNN; k++) t5[r][k] = 1e300;
    double rowmax = 0.0;

    for (int jt = 0; jt < JTILES; jt++) {
        int j0 = jbase + jt * TJ;
        __syncthreads();
        if (t < TJ) Sqj[t] = sq[j0 + t];
        #pragma unroll
        for (int q = 0; q < 8; q++) {
            int flat = t + 256 * q;
            int row = flat >> 5, c4 = flat & 31;
            float4 v = X4[(size_t)(j0 + row) * 32 + c4];
            float* dst = &Bs[(4 * c4) * LDSROW + row];
            dst[0 * LDSROW] = v.x; dst[1 * LDSROW] = v.y;
            dst[2 * LDSROW] = v.z; dst[3 * LDSROW] = v.w;
        }
        __syncthreads();

        double acc[4][4];
        #pragma unroll
        for (int r = 0; r < 4; r++)
            #pragma unroll
            for (int s = 0; s < 4; s++) acc[r][s] = 0.0;

        #pragma unroll 4
        for (int c = 0; c < C; c++) {
            float4 af = *(const float4*)&As[c * LDSROW + 4 * ty];
            float4 bf = *(const float4*)&Bs[c * LDSROW + 4 * tx];
            double a0 = af.x, a1 = af.y, a2 = af.z, a3 = af.w;
            double b0 = bf.x, b1 = bf.y, b2 = bf.z, b3 = bf.w;
            acc[0][0] += a0 * b0; acc[0][1] += a0 * b1; acc[0][2] += a0 * b2; acc[0][3] += a0 * b3;
            acc[1][0] += a1 * b0; acc[1][1] += a1 * b1; acc[1][2] += a1 * b2; acc[1][3] += a1 * b3;
            acc[2][0] += a2 * b0; acc[2][1] += a2 * b1; acc[2][2] += a2 * b2; acc[2][3] += a2 * b3;
            acc[3][0] += a3 * b0; acc[3][1] += a3 * b1; acc[3][2] += a3 * b2; acc[3][3] += a3 * b3;
        }

        #pragma unroll
        for (int r = 0; r < 4; r++) {
            #pragma unroll
            for (int s = 0; s < 4; s++) {
                double v = sqa[r] + Sqj[4 * tx + s] - 2.0 * acc[r][s];
                rowmax = fmax(rowmax, v);
                if (v < t5[r][0]) {       // t5[r][0] = current max of the 5
                    t5[r][0] = v;
                    #pragma unroll
                    for (int k = 1; k < KNN; k++)
                        if (t5[r][k] > t5[r][0]) { double tmp = t5[r][0]; t5[r][0] = t5[r][k]; t5[r][k] = tmp; }
                }
            }
        }
    }

    // wave-level rowmax reduce (before LDS reuse)
    double tmax = rowmax;
    #pragma unroll
    for (int off = 32; off > 0; off >>= 1) tmax = fmax(tmax, __shfl_down(tmax, off, 64));
    if ((t & 63) == 0) wmax[t >> 6] = tmax;

    __syncthreads();   // all waves done with As/Bs and wmax written

    // block merge of per-thread top5 via LDS (reuse S): M[row][16*5]
    double* M = (double*)S;
    #pragma unroll
    for (int r = 0; r < 4; r++)
        #pragma unroll
        for (int k = 0; k < KNN; k++)
            M[(4 * ty + r) * 80 + tx * KNN + k] = t5[r][k];
    __syncthreads();

    if (t == 0) {
        double bm = fmax(fmax(wmax[0], wmax[1]), fmax(wmax[2], wmax[3]));
        bm = fmax(bm, 0.0);
        atomicMax(d2max_p, (unsigned long long)__double_as_longlong(bm));
    }
    if (t < TI) {
        double m5[KNN];
        #pragma unroll
        for (int k = 0; k < KNN; k++) m5[k] = 1e300;
        const double* row = &M[t * 80];
        for (int q = 0; q < 80; q++) {
            double v = row[q];
            if (v < m5[0]) {
                m5[0] = v;
                #pragma unroll
                for (int k = 1; k < KNN; k++)
                    if (m5[k] > m5[0]) { double tmp = m5[0]; m5[0] = m5[k]; m5[k] = tmp; }
            }
        }
        double* outp = &top5part[((size_t)js * N + (i0 + t)) * KNN];
        #pragma unroll
        for (int k = 0; k < KNN; k++) outp[k] = m5[k];
    }
}

// ---------------------------------------------------------------------------
// Merge pass-A partials -> density (exact round-1 formula)
// ---------------------------------------------------------------------------
__global__ void density_merge_kernel(const double* __restrict__ top5part,
                                     const float* __restrict__ noise,
                                     double* __restrict__ density)
{
    int i = blockIdx.x * blockDim.x + threadIdx.x;
    if (i >= N) return;
    double t5[KNN];
    #pragma unroll
    for (int k = 0; k < KNN; k++) t5[k] = 1e300;
    for (int js = 0; js < JSPLIT; js++) {
        const double* p = &top5part[((size_t)js * N + i) * KNN];
        #pragma unroll
        for (int k = 0; k < KNN; k++) {
            double v = p[k];
            if (v < t5[0]) {
                t5[0] = v;
                #pragma unroll
                for (int q = 1; q < KNN; q++)
                    if (t5[q] > t5[0]) { double tmp = t5[0]; t5[0] = t5[q]; t5[q] = tmp; }
            }
        }
    }
    // sort ascending; sum in ascending order (matches reference / round 1)
    for (int a = 1; a < KNN; a++) {
        double key = t5[a]; int b = a - 1;
        while (b >= 0 && t5[b] > key) { t5[b + 1] = t5[b]; b--; }
        t5[b + 1] = key;
    }
    double s2 = 0.0;
    #pragma unroll
    for (int k = 0; k < KNN; k++) {
        double z = t5[k] > 0.0 ? t5[k] : 0.0;
        double d = sqrt(z) / INV_SQRT_C;
        s2 += d * d;
    }
    double m = s2 / 5.0;
    density[i] = exp(-m) + (double)(noise[i] * 1e-6f);
}

// ---------------------------------------------------------------------------
// Pass B (partial): masked min of d2 over j with density[j] > density[i].
// ---------------------------------------------------------------------------
__launch_bounds__(256, 2)
__global__ void parent_partial_kernel(const float* __restrict__ X,
                                      const double* __restrict__ sq,
                                      const double* __restrict__ density,
                                      double* __restrict__ minpart)  // [JSPLIT][N]
{
    __shared__ __align__(16) float S[2 * C * LDSROW];
    __shared__ double Sqj[TJ];
    __shared__ double Dj[TJ];
    float* As = S;
    float* Bs = S + C * LDSROW;

    const int t  = threadIdx.x;
    const int tx = t & 15;
    const int ty = t >> 4;
    const int i0 = (blockIdx.x & 127) * TI;
    const int js = blockIdx.x >> 7;
    const int jbase = js * (N / JSPLIT);

    const float4* X4 = (const float4*)X;

    #pragma unroll
    for (int q = 0; q < 8; q++) {
        int flat = t + 256 * q;
        int row = flat >> 5, c4 = flat & 31;
        float4 v = X4[(size_t)(i0 + row) * 32 + c4];
        float* dst = &As[(4 * c4) * LDSROW + row];
        dst[0 * LDSROW] = v.x; dst[1 * LDSROW] = v.y;
        dst[2 * LDSROW] = v.z; dst[3 * LDSROW] = v.w;
    }

    double sqa[4], di[4], dmin[4];
    #pragma unroll
    for (int r = 0; r < 4; r++) {
        sqa[r] = sq[i0 + 4 * ty + r];
        di[r]  = density[i0 + 4 * ty + r];
        dmin[r] = 1e300;
    }

    for (int jt = 0; jt < JTILES; jt++) {
        int j0 = jbase + jt * TJ;
        __syncthreads();
        if (t < TJ) { Sqj[t] = sq[j0 + t]; Dj[t] = density[j0 + t]; }
        #pragma unroll
        for (int q = 0; q < 8; q++) {
            int flat = t + 256 * q;
            int row = flat >> 5, c4 = flat & 31;
            float4 v = X4[(size_t)(j0 + row) * 32 + c4];
            float* dst = &Bs[(4 * c4) * LDSROW + row];
            dst[0 * LDSROW] = v.x; dst[1 * LDSROW] = v.y;
            dst[2 * LDSROW] = v.z; dst[3 * LDSROW] = v.w;
        }
        __syncthreads();

        double acc[4][4];
        #pragma unroll
        for (int r = 0; r < 4; r++)
            #pragma unroll
            for (int s = 0; s < 4; s++) acc[r][s] = 0.0;

        #pragma unroll 4
        for (int c = 0; c < C; c++) {
            float4 af = *(const float4*)&As[c * LDSROW + 4 * ty];
            float4 bf = *(const float4*)&Bs[c * LDSROW + 4 * tx];
            double a0 = af.x, a1 = af.y, a2 = af.z, a3 = af.w;
            double b0 = bf.x, b1 = bf.y, b2 = bf.z, b3 = bf.w;
            acc[0][0] += a0 * b0; acc[0][1] += a0 * b1; acc[0][2] += a0 * b2; acc[0][3] += a0 * b3;
            acc[1][0] += a1 * b0; acc[1][1] += a1 * b1; acc[1][2] += a1 * b2; acc[1][3] += a1 * b3;
            acc[2][0] += a2 * b0; acc[2][1] += a2 * b1; acc[2][2] += a2 * b2; acc[2][3] += a2 * b3;
            acc[3][0] += a3 * b0; acc[3][1] += a3 * b1; acc[3][2] += a3 * b2; acc[3][3] += a3 * b3;
        }

        #pragma unroll
        for (int r = 0; r < 4; r++) {
            #pragma unroll
            for (int s = 0; s < 4; s++) {
                double v = sqa[r] + Sqj[4 * tx + s] - 2.0 * acc[r][s];
                if (Dj[4 * tx + s] > di[r]) dmin[r] = fmin(dmin[r], v);
            }
        }
    }

    __syncthreads();
    double* M = (double*)S;   // M[row][16]
    #pragma unroll
    for (int r = 0; r < 4; r++) M[(4 * ty + r) * 16 + tx] = dmin[r];
    __syncthreads();
    if (t < TI) {
        double m = 1e300;
        const double* row = &M[t * 16];
        #pragma unroll
        for (int q = 0; q < 16; q++) m = fmin(m, row[q]);
        minpart[(size_t)js * N + (i0 + t)] = m;
    }
}

// ---------------------------------------------------------------------------
// Merge pass-B partials -> score (exact round-1 formula)
// ---------------------------------------------------------------------------
__global__ void score_merge_kernel(const double* __restrict__ minpart,
                                   const double* __restrict__ density,
                                   const unsigned long long* __restrict__ d2max_p,
                                   double* __restrict__ score)
{
    int i = blockIdx.x * blockDim.x + threadIdx.x;
    if (i >= N) return;
    double dmin = 1e300;
    for (int js = 0; js < JSPLIT; js++) dmin = fmin(dmin, minpart[(size_t)js * N + i]);
    double d2m = __longlong_as_double((long long)(*d2max_p));
    double distmax = sqrt(fmax(d2m, 0.0)) / INV_SQRT_C;
    double dp = (dmin > 9.9e299) ? distmax : sqrt(fmax(dmin, 0.0)) / INV_SQRT_C;
    score[i] = dp * density[i];
}

// ---------------------------------------------------------------------------
// Stable descending rank; out[rank] = i.  -- identical to R1
// ---------------------------------------------------------------------------
__launch_bounds__(256)
__global__ void rank_kernel(const double* __restrict__ score, int* __restrict__ out)
{
    __shared__ double Ss[N];
    #pragma unroll
    for (int k = 0; k < N / 256; k++) {
        int idx = threadIdx.x + 256 * k;
        Ss[idx] = score[idx];
    }
    __syncthreads();
    int i = blockIdx.x * 256 + threadIdx.x;
    double si = Ss[i];
    int rank = 0;
    for (int j = 0; j < N; j++) {
        double sj = Ss[j];
        rank += (sj > si) || (sj == si && j < i);
    }
    if (rank < NC) out[rank] = i;
}

// ---------------------------------------------------------------------------
extern "C" void kernel_launch(void* const* d_in, const int* in_sizes, int n_in,
                              void* d_out, int out_size, void* d_ws, size_t ws_size,
                              hipStream_t stream) {
    const float* X = (const float*)d_in[0];
    int* out = (int*)d_out;

    double* ws      = (double*)d_ws;
    double* sq      = ws;                      // 8192
    double* density = ws + 8192;               // 8192
    double* score   = ws + 16384;              // 8192
    unsigned long long* d2max = (unsigned long long*)(ws + 24576);  // 1 (+pad)
    float*  noise   = (float*)(ws + 24584);    // 8192 floats (4096 dbl slots)
    double* top5part = ws + 28680;             // JSPLIT*N*5 = 327680
    double* minpart  = ws + 28680 + (size_t)JSPLIT * N * KNN;  // JSPLIT*N = 65536

    init_kernel<<<1, 1, 0, stream>>>(d2max);
    sq_kernel<<<N / 4, 256, 0, stream>>>(X, sq);
    noise_kernel<<<(N / 2) / 256, 256, 0, stream>>>(noise);
    density_partial_kernel<<<(N / TI) * JSPLIT, 256, 0, stream>>>(X, sq, top5part, d2max);
    density_merge_kernel<<<N / 256, 256, 0, stream>>>(top5part, noise, density);
    parent_partial_kernel<<<(N / TI) * JSPLIT, 256, 0, stream>>>(X, sq, density, minpart);
    score_merge_kernel<<<N / 256, 256, 0, stream>>>(minpart, density, d2max, score);
    rank_kernel<<<N / 256, 256, 0, stream>>>(score, out);
}